// Round 1
// baseline (331.984 us; speedup 1.0000x reference)
//
#include <hip/hip_runtime.h>

// QuantLinearFP8: out[m,n] = sum_k x[m,k] * w[n,k] * scale[n, k/128] + bias[n]
// M=64, K=4096, N=11008, G=128 (32 groups).
//
// Strategy: bf16 MFMA (weights are fp8-e4m3 values -> exact in bf16; only x
// rounds). Per-group f32 partial accumulation, scale applied in f32.
// Block = 256 thr = 4 waves; block owns a 16-wide N tile; each wave owns one
// K-quarter (1024 = 8 groups) and a full 64xM x 16xN partial; LDS reduction
// across the 4 waves at the end.

#define Md 64
#define Kd 4096
#define Nd 11008
#define NGROUPS 32

typedef __attribute__((ext_vector_type(8))) __bf16 bf16x8;
typedef __attribute__((ext_vector_type(4))) float f32x4;

__global__ __launch_bounds__(256)
void qlinear_fp8_kernel(const float* __restrict__ x,
                        const float* __restrict__ w,
                        const float* __restrict__ scale,
                        const float* __restrict__ bias,
                        float* __restrict__ out)
{
    const int tid  = threadIdx.x;
    const int wv   = tid >> 6;        // wave id 0..3 -> k-quarter
    const int lane = tid & 63;
    const int quad = lane >> 4;       // 0..3 -> k-subblock of 8
    const int ln   = lane & 15;       // n (B-frag col) / m (A-frag row)

    const int n0 = blockIdx.x * 16;
    const int n  = n0 + ln;

    const int kq = wv * (Kd / 4);     // this wave's k-quarter base

    // B-frag source: w[n][kq + quad*8 + j + k], j=0..7 (8 contiguous f32)
    const float* wp = w + (size_t)n * Kd + kq + quad * 8;
    // A-frag source (tile t): x[t*16 + ln][kq + quad*8 + j + k]
    const float* xp = x + (size_t)ln * Kd + kq + quad * 8;

    f32x4 acc[4];
    #pragma unroll
    for (int t = 0; t < 4; ++t) acc[t] = (f32x4){0.f, 0.f, 0.f, 0.f};

    for (int g = 0; g < 8; ++g) {          // 8 groups of 128 in this quarter
        f32x4 pg[4];
        #pragma unroll
        for (int t = 0; t < 4; ++t) pg[t] = (f32x4){0.f, 0.f, 0.f, 0.f};

        #pragma unroll
        for (int ks = 0; ks < 4; ++ks) {   // 128 / 32 k-steps
            const int k = g * 128 + ks * 32;

            float4 w0 = *(const float4*)(wp + k);
            float4 w1 = *(const float4*)(wp + k + 4);
            bf16x8 bf;
            bf[0] = (__bf16)w0.x; bf[1] = (__bf16)w0.y;
            bf[2] = (__bf16)w0.z; bf[3] = (__bf16)w0.w;
            bf[4] = (__bf16)w1.x; bf[5] = (__bf16)w1.y;
            bf[6] = (__bf16)w1.z; bf[7] = (__bf16)w1.w;

            #pragma unroll
            for (int t = 0; t < 4; ++t) {
                const float* xt = xp + (size_t)(t * 16) * Kd + k;
                float4 x0 = *(const float4*)(xt);
                float4 x1 = *(const float4*)(xt + 4);
                bf16x8 af;
                af[0] = (__bf16)x0.x; af[1] = (__bf16)x0.y;
                af[2] = (__bf16)x0.z; af[3] = (__bf16)x0.w;
                af[4] = (__bf16)x1.x; af[5] = (__bf16)x1.y;
                af[6] = (__bf16)x1.z; af[7] = (__bf16)x1.w;

                pg[t] = __builtin_amdgcn_mfma_f32_16x16x32_bf16(af, bf, pg[t],
                                                                0, 0, 0);
            }
        }

        // Apply this group's dequant scale in f32 (exact), fold into total.
        const float s = scale[(size_t)n * NGROUPS + wv * 8 + g];
        #pragma unroll
        for (int t = 0; t < 4; ++t) {
            #pragma unroll
            for (int r = 0; r < 4; ++r)
                acc[t][r] += s * pg[t][r];
        }
    }

    // Cross-wave (k-quarter) reduction via LDS. C/D layout: col = lane&15,
    // row = quad*4 + reg. Pad inner dim 16->17 to break 4-way bank aliasing.
    __shared__ float red[4][64][17];
    #pragma unroll
    for (int t = 0; t < 4; ++t) {
        #pragma unroll
        for (int r = 0; r < 4; ++r)
            red[wv][t * 16 + quad * 4 + r][ln] = acc[t][r];
    }
    __syncthreads();

    // 256 threads -> 64x16 outputs, 4 each.
    const int m  = tid >> 2;
    const int nq = (tid & 3) * 4;
    #pragma unroll
    for (int j = 0; j < 4; ++j) {
        const int nn = nq + j;
        float v = red[0][m][nn] + red[1][m][nn] + red[2][m][nn]
                + red[3][m][nn] + bias[n0 + nn];
        out[(size_t)m * Nd + n0 + nn] = v;
    }
}

extern "C" void kernel_launch(void* const* d_in, const int* in_sizes, int n_in,
                              void* d_out, int out_size, void* d_ws, size_t ws_size,
                              hipStream_t stream) {
    const float* x     = (const float*)d_in[0];  // [64][4096]
    const float* w     = (const float*)d_in[1];  // [11008][4096]
    const float* scale = (const float*)d_in[2];  // [11008][32]
    const float* bias  = (const float*)d_in[3];  // [11008]
    float* out = (float*)d_out;                  // [64][11008] f32

    qlinear_fp8_kernel<<<Nd / 16, 256, 0, stream>>>(x, w, scale, bias, out);
}

// Round 2
// 291.889 us; speedup vs baseline: 1.1374x; 1.1374x over previous
//
#include <hip/hip_runtime.h>

// QuantLinearFP8: out[m,n] = sum_k x[m,k] * w[n,k] * scale[n, k/128] + bias[n]
// M=64, K=4096, N=11008, G=128.
//
// R2 structure: canonical LDS-staged bf16 MFMA GEMM, K-split 4 for occupancy.
//  - Pass 1 (688 blocks = 172 n-tiles x 4 k-chunks, 256 thr):
//      per 128-k iter: coalesced f32 global loads (16x float4/thread, issued
//      up-front), cvt->bf16, LDS (pad +8 -> only 2-way bank alias, free),
//      ds_read_b128 fragments, mfma 16x16x32. BK=128 == one scale group.
//      Each wave owns a 16-wide n-stripe (no cross-wave reduction).
//      Partials -> ws[4][64][11008] f32.
//  - Pass 2: reduce 4 partials + bias -> out (deterministic; also avoids
//      needing to zero-init poisoned d_out).

#define Md 64
#define Kd 4096
#define Nd 11008
#define NGROUPS 32
#define BK 128
#define BN 64
#define KSPLIT 4
#define KCHUNK (Kd / KSPLIT)     // 1024
#define NITER (KCHUNK / BK)      // 8
#define LDSS (BK + 8)            // 136 bf16 row stride = 272 B (16B-aligned)

typedef __attribute__((ext_vector_type(8))) __bf16 bf16x8;
typedef __attribute__((ext_vector_type(4))) __bf16 bf16x4;
typedef __attribute__((ext_vector_type(4))) float f32x4;

__global__ __launch_bounds__(256, 4)
void qlinear_pass1(const float* __restrict__ x,
                   const float* __restrict__ w,
                   const float* __restrict__ scale,
                   float* __restrict__ ws)
{
    const int tid  = threadIdx.x;
    const int wv   = tid >> 6;         // wave 0..3 -> n-substripe
    const int lane = tid & 63;
    const int quad = lane >> 4;
    const int ln   = lane & 15;

    const int n0 = blockIdx.x * BN;    // n-tile base
    const int ky = blockIdx.y;         // k-chunk 0..3
    const int k0 = ky * KCHUNK;

    // ---- staging thread mapping: float4 col + base row ----
    const int col4 = tid & 31;         // float4 index within 128-k row chunk
    const int row0 = tid >> 5;         // 0..7; rows row0 + 8*j
    const float* wsrc = w + (size_t)(n0 + row0) * Kd + k0 + col4 * 4;
    const float* xsrc = x + (size_t)row0 * Kd + k0 + col4 * 4;

    __shared__ __bf16 lds_w[BN * LDSS];
    __shared__ __bf16 lds_x[Md * LDSS];

    // preload this lane's 8 group scales (contiguous 32B)
    const int ng = n0 + wv * 16 + ln;
    float sc[8];
    {
        const float* sp = scale + (size_t)ng * NGROUPS + ky * NITER;
        float4 s0 = *(const float4*)(sp);
        float4 s1 = *(const float4*)(sp + 4);
        sc[0]=s0.x; sc[1]=s0.y; sc[2]=s0.z; sc[3]=s0.w;
        sc[4]=s1.x; sc[5]=s1.y; sc[6]=s1.z; sc[7]=s1.w;
    }

    f32x4 acc[4];
    #pragma unroll
    for (int t = 0; t < 4; ++t) acc[t] = (f32x4){0.f, 0.f, 0.f, 0.f};

    float4 wreg[8], xreg[8];
    // issue all 16 loads of iter 0 (independent -> deep MLP)
    #pragma unroll
    for (int j = 0; j < 8; ++j) {
        wreg[j] = *(const float4*)(wsrc + (size_t)(8 * j) * Kd);
        xreg[j] = *(const float4*)(xsrc + (size_t)(8 * j) * Kd);
    }

    for (int i = 0; i < NITER; ++i) {
        // cvt + LDS write
        #pragma unroll
        for (int j = 0; j < 8; ++j) {
            const int off = (row0 + 8 * j) * LDSS + col4 * 4;
            float4 v = wreg[j];
            *(bf16x4*)&lds_w[off] =
                (bf16x4){(__bf16)v.x, (__bf16)v.y, (__bf16)v.z, (__bf16)v.w};
            float4 u = xreg[j];
            *(bf16x4*)&lds_x[off] =
                (bf16x4){(__bf16)u.x, (__bf16)u.y, (__bf16)u.z, (__bf16)u.w};
        }
        __syncthreads();

        // prefetch next iter's globals (issued before the compute)
        if (i + 1 < NITER) {
            const float* wp = wsrc + (i + 1) * BK;
            const float* xp = xsrc + (i + 1) * BK;
            #pragma unroll
            for (int j = 0; j < 8; ++j) {
                wreg[j] = *(const float4*)(wp + (size_t)(8 * j) * Kd);
                xreg[j] = *(const float4*)(xp + (size_t)(8 * j) * Kd);
            }
        }

        // compute: 4 k-steps of 32, one scale group total
        f32x4 pg[4];
        #pragma unroll
        for (int t = 0; t < 4; ++t) pg[t] = (f32x4){0.f, 0.f, 0.f, 0.f};

        #pragma unroll
        for (int ks = 0; ks < 4; ++ks) {
            const int ko = ks * 32 + quad * 8;
            bf16x8 wf = *(const bf16x8*)&lds_w[(wv * 16 + ln) * LDSS + ko];
            #pragma unroll
            for (int t = 0; t < 4; ++t) {
                bf16x8 xf = *(const bf16x8*)&lds_x[(t * 16 + ln) * LDSS + ko];
                pg[t] = __builtin_amdgcn_mfma_f32_16x16x32_bf16(xf, wf, pg[t],
                                                                0, 0, 0);
            }
        }

        const float s = sc[i];
        #pragma unroll
        for (int t = 0; t < 4; ++t)
            #pragma unroll
            for (int r = 0; r < 4; ++r)
                acc[t][r] += s * pg[t][r];

        __syncthreads();   // LDS safe to overwrite next iter
    }

    // partials -> ws[ky][m][n]  (C/D: m = t*16 + quad*4 + r, n col = ln)
    float* wp = ws + ((size_t)ky * Md) * Nd + n0 + wv * 16 + ln;
    #pragma unroll
    for (int t = 0; t < 4; ++t)
        #pragma unroll
        for (int r = 0; r < 4; ++r)
            wp[(size_t)(t * 16 + quad * 4 + r) * Nd] = acc[t][r];
}

__global__ __launch_bounds__(256)
void qlinear_reduce(const float* __restrict__ ws,
                    const float* __restrict__ bias,
                    float* __restrict__ out)
{
    const int idx = blockIdx.x * 256 + threadIdx.x;
    if (idx >= Md * Nd) return;
    const int n = idx % Nd;
    float v = bias[n];
    #pragma unroll
    for (int ky = 0; ky < KSPLIT; ++ky)
        v += ws[(size_t)ky * Md * Nd + idx];
    out[idx] = v;
}

extern "C" void kernel_launch(void* const* d_in, const int* in_sizes, int n_in,
                              void* d_out, int out_size, void* d_ws, size_t ws_size,
                              hipStream_t stream) {
    const float* x     = (const float*)d_in[0];  // [64][4096]
    const float* w     = (const float*)d_in[1];  // [11008][4096]
    const float* scale = (const float*)d_in[2];  // [11008][32]
    const float* bias  = (const float*)d_in[3];  // [11008]
    float* out = (float*)d_out;                  // [64][11008] f32
    float* ws  = (float*)d_ws;                   // [4][64][11008] f32 = 11.3 MB

    dim3 grid1(Nd / BN, KSPLIT);
    qlinear_pass1<<<grid1, 256, 0, stream>>>(x, w, scale, ws);

    const int total = Md * Nd;                   // 704512 = 2752 * 256
    qlinear_reduce<<<(total + 255) / 256, 256, 0, stream>>>(ws, bias, out);
}

// Round 3
// 274.821 us; speedup vs baseline: 1.2080x; 1.0621x over previous
//
#include <hip/hip_runtime.h>

// QuantLinearFP8: out[m,n] = sum_k x[m,k] * w[n,k] * scale[n, k/128] + bias[n]
// M=64, K=4096, N=11008, G=128.
//
// R3: w is single-use -> stream it global->register directly in B-frag
// layout (no LDS round-trip). Only x (reused by all n) is staged in LDS as
// bf16 (+8 pad, conflict-free). BK=64, register double-buffer of next iter's
// 8 float4 loads. KSPLIT=8 -> 1376 blocks (5.4/CU) for latency hiding.
// Partials -> ws, pass 2 reduces + bias (deterministic, overwrites poison).

#define Md 64
#define Kd 4096
#define Nd 11008
#define NGROUPS 32
#define BN 64
#define BK 64
#define KSPLIT 8
#define KCHUNK (Kd / KSPLIT)     // 512
#define NITER (KCHUNK / BK)      // 8
#define NGRP (KCHUNK / 128)      // 4 scale groups per chunk
#define XLD (BK + 8)             // 72 bf16 row stride = 144 B (16B-aligned)

typedef __attribute__((ext_vector_type(8))) __bf16 bf16x8;
typedef __attribute__((ext_vector_type(4))) float f32x4;

__global__ __launch_bounds__(256, 4)
void qlinear_pass1(const float* __restrict__ x,
                   const float* __restrict__ w,
                   const float* __restrict__ scale,
                   float* __restrict__ ws)
{
    const int tid  = threadIdx.x;
    const int wv   = tid >> 6;         // wave -> n-substripe
    const int lane = tid & 63;
    const int quad = lane >> 4;
    const int ln   = lane & 15;

    const int n0 = blockIdx.x * BN;
    const int ky = blockIdx.y;
    const int k0 = ky * KCHUNK;

    // B-frag source: lane (quad,ln) holds w[nrow][kbase + quad*8 + j]
    const int nrow = n0 + wv * 16 + ln;
    const float* wp = w + (size_t)nrow * Kd + k0 + quad * 8;

    // x staging: thread -> (row, 16-float chunk)
    const int xrow = tid >> 2;
    const int xc0  = (tid & 3) * 16;
    const float* xp = x + (size_t)xrow * Kd + k0 + xc0;

    __shared__ __bf16 lds_x[Md * XLD];

    // 4 group scales for this chunk (contiguous 16 B)
    float4 sc4 = *(const float4*)(scale + (size_t)nrow * NGROUPS + ky * NGRP);
    const float sc[4] = {sc4.x, sc4.y, sc4.z, sc4.w};

    f32x4 acc[4];
    #pragma unroll
    for (int t = 0; t < 4; ++t) acc[t] = (f32x4){0.f, 0.f, 0.f, 0.f};

    // register double-buffer: 4 w float4 + 4 x float4 per iter
    float4 wreg[2][4], xreg[2][4];
    #pragma unroll
    for (int j = 0; j < 4; ++j)
        xreg[0][j] = *(const float4*)(xp + j * 4);
    wreg[0][0] = *(const float4*)(wp + 0);
    wreg[0][1] = *(const float4*)(wp + 4);
    wreg[0][2] = *(const float4*)(wp + 32);
    wreg[0][3] = *(const float4*)(wp + 36);

    #pragma unroll
    for (int g = 0; g < NGRP; ++g) {
        f32x4 pg[4];
        #pragma unroll
        for (int t = 0; t < 4; ++t) pg[t] = (f32x4){0.f, 0.f, 0.f, 0.f};

        #pragma unroll
        for (int sub = 0; sub < 2; ++sub) {
            const int i   = g * 2 + sub;
            const int buf = i & 1;

            // stage x: cvt f32->bf16, write 2x b128
            #pragma unroll
            for (int j = 0; j < 2; ++j) {
                float4 a = xreg[buf][2 * j], b = xreg[buf][2 * j + 1];
                bf16x8 v = {(__bf16)a.x, (__bf16)a.y, (__bf16)a.z, (__bf16)a.w,
                            (__bf16)b.x, (__bf16)b.y, (__bf16)b.z, (__bf16)b.w};
                *(bf16x8*)&lds_x[xrow * XLD + xc0 + j * 8] = v;
            }
            __syncthreads();

            // prefetch next iter's globals (hidden under compute)
            if (i + 1 < NITER) {
                const int nb = buf ^ 1;
                #pragma unroll
                for (int j = 0; j < 4; ++j)
                    xreg[nb][j] = *(const float4*)(xp + (i + 1) * BK + j * 4);
                wreg[nb][0] = *(const float4*)(wp + (i + 1) * BK + 0);
                wreg[nb][1] = *(const float4*)(wp + (i + 1) * BK + 4);
                wreg[nb][2] = *(const float4*)(wp + (i + 1) * BK + 32);
                wreg[nb][3] = *(const float4*)(wp + (i + 1) * BK + 36);
            }

            // compute: 2 k-steps of 32
            #pragma unroll
            for (int ks = 0; ks < 2; ++ks) {
                float4 wa = wreg[buf][2 * ks], wb = wreg[buf][2 * ks + 1];
                bf16x8 wf = {(__bf16)wa.x, (__bf16)wa.y, (__bf16)wa.z, (__bf16)wa.w,
                             (__bf16)wb.x, (__bf16)wb.y, (__bf16)wb.z, (__bf16)wb.w};
                #pragma unroll
                for (int t = 0; t < 4; ++t) {
                    bf16x8 xf = *(const bf16x8*)
                        &lds_x[(t * 16 + ln) * XLD + ks * 32 + quad * 8];
                    pg[t] = __builtin_amdgcn_mfma_f32_16x16x32_bf16(xf, wf, pg[t],
                                                                    0, 0, 0);
                }
            }
            __syncthreads();   // LDS safe to overwrite next iter
        }

        const float s = sc[g];
        #pragma unroll
        for (int t = 0; t < 4; ++t)
            #pragma unroll
            for (int r = 0; r < 4; ++r)
                acc[t][r] += s * pg[t][r];
    }

    // partials -> ws[ky][m][n]  (C/D: m = t*16 + quad*4 + r, col = ln)
    float* op = ws + ((size_t)ky * Md) * Nd + n0 + wv * 16 + ln;
    #pragma unroll
    for (int t = 0; t < 4; ++t)
        #pragma unroll
        for (int r = 0; r < 4; ++r)
            op[(size_t)(t * 16 + quad * 4 + r) * Nd] = acc[t][r];
}

__global__ __launch_bounds__(256)
void qlinear_reduce(const float* __restrict__ ws,
                    const float* __restrict__ bias,
                    float* __restrict__ out)
{
    const int idx = blockIdx.x * 256 + threadIdx.x;
    if (idx >= Md * Nd) return;
    const int n = idx % Nd;
    float v = bias[n];
    #pragma unroll
    for (int ky = 0; ky < KSPLIT; ++ky)
        v += ws[(size_t)ky * Md * Nd + idx];
    out[idx] = v;
}

extern "C" void kernel_launch(void* const* d_in, const int* in_sizes, int n_in,
                              void* d_out, int out_size, void* d_ws, size_t ws_size,
                              hipStream_t stream) {
    const float* x     = (const float*)d_in[0];  // [64][4096]
    const float* w     = (const float*)d_in[1];  // [11008][4096]
    const float* scale = (const float*)d_in[2];  // [11008][32]
    const float* bias  = (const float*)d_in[3];  // [11008]
    float* out = (float*)d_out;                  // [64][11008] f32
    float* ws  = (float*)d_ws;                   // [8][64][11008] f32 = 22.5 MB

    dim3 grid1(Nd / BN, KSPLIT);
    qlinear_pass1<<<grid1, 256, 0, stream>>>(x, w, scale, ws);

    const int total = Md * Nd;                   // 704512 = 2752 * 256
    qlinear_reduce<<<(total + 255) / 256, 256, 0, stream>>>(ws, bias, out);
}